// Round 1
// baseline (262.790 us; speedup 1.0000x reference)
//
#include <hip/hip_runtime.h>

#define NA_TOT 8400
#define A0 6400
#define A1 8000
#define NC_TOT 144
#define BSZ 16
#define MB 20
#define TOPKN 10
#define NCLS 80

// ---------- helpers ----------

__device__ __forceinline__ const float* feat_sel(const float* f0, const float* f1,
                                                 const float* f2, int a, int& hw, int& pos) {
  if (a < A0) { hw = 6400; pos = a;      return f0; }
  if (a < A1) { hw = 1600; pos = a - A0; return f1; }
  hw = 400; pos = a - A1; return f2;
}

__device__ __forceinline__ void anchor_geom(int a, float& stride, float& ax, float& ay) {
  int pos, w;
  if (a < A0)      { pos = a;      w = 80; stride = 8.f;  }
  else if (a < A1) { pos = a - A0; w = 40; stride = 16.f; }
  else             { pos = a - A1; w = 20; stride = 32.f; }
  int y = pos / w, x = pos - y * w;
  ax = (float)x + 0.5f; ay = (float)y + 0.5f;
}

// CIoU exactly per reference (_ciou). b1 = first arg box, b2 = second.
__device__ __forceinline__ float ciou_f(float b1x1, float b1y1, float b1x2, float b1y2,
                                        float b2x1, float b2y1, float b2x2, float b2y2) {
  const float eps = 1e-7f;
  float w1 = b1x2 - b1x1, h1 = b1y2 - b1y1 + eps;
  float w2 = b2x2 - b2x1, h2 = b2y2 - b2y1 + eps;
  float iw = fminf(b1x2, b2x2) - fmaxf(b1x1, b2x1);
  float ih = fminf(b1y2, b2y2) - fmaxf(b1y1, b2y1);
  float inter = fmaxf(iw, 0.f) * fmaxf(ih, 0.f);
  float uni = w1 * h1 + w2 * h2 - inter + eps;
  float iou = inter / uni;
  float cw = fmaxf(b1x2, b2x2) - fminf(b1x1, b2x1);
  float ch = fmaxf(b1y2, b2y2) - fminf(b1y1, b2y1);
  float c2 = cw * cw + ch * ch + eps;
  float dx = b2x1 + b2x2 - b1x1 - b1x2;
  float dy = b2y1 + b2y2 - b1y1 - b1y2;
  float rho2 = (dx * dx + dy * dy) * 0.25f;
  float dat = atanf(w2 / h2) - atanf(w1 / h1);
  float v = 0.4052847345693511f * dat * dat;      // 4/pi^2
  float alpha = v / (v - iou + (1.f + eps));
  return iou - (rho2 / c2 + v * alpha);
}

// ---------- K1: per-anchor prep (dist/softmax, lse, pred boxes) + bce(x,0) sum ----------

__global__ __launch_bounds__(256) void k_prep(const float* __restrict__ f0,
                                              const float* __restrict__ f1,
                                              const float* __restrict__ f2,
                                              float4* __restrict__ pbox,
                                              float4* __restrict__ lse4,
                                              double* __restrict__ acc) {
  int idx = blockIdx.x * 256 + threadIdx.x;          // exactly BSZ*NA_TOT threads
  int b = idx / NA_TOT, a = idx - b * NA_TOT;
  int hw, pos;
  const float* f = feat_sel(f0, f1, f2, a, hw, pos);
  float stride, ax, ay; anchor_geom(a, stride, ax, ay);
  const float* base = f + (size_t)b * NC_TOT * hw + pos;

  float d[4], ls[4];
#pragma unroll
  for (int g = 0; g < 4; g++) {
    float v[16]; float m = -1e30f;
#pragma unroll
    for (int i = 0; i < 16; i++) { v[i] = base[(size_t)(g * 16 + i) * hw]; m = fmaxf(m, v[i]); }
    float s = 0.f, ws = 0.f;
#pragma unroll
    for (int i = 0; i < 16; i++) { float e = expf(v[i] - m); s += e; ws += e * (float)i; }
    d[g] = ws / s;
    ls[g] = m + logf(s);
  }
  pbox[idx] = make_float4(ax - d[0], ay - d[1], ax + d[2], ay + d[3]);
  lse4[idx] = make_float4(ls[0], ls[1], ls[2], ls[3]);

  float bce = 0.f;
#pragma unroll 8
  for (int c = 0; c < NCLS; c++) {
    float x = base[(size_t)(64 + c) * hw];
    bce += fmaxf(x, 0.f) + log1pf(expf(-fabsf(x)));
  }
  for (int o = 32; o > 0; o >>= 1) bce += __shfl_down(bce, o, 64);
  __shared__ float sred[4];
  if ((threadIdx.x & 63) == 0) sred[threadIdx.x >> 6] = bce;
  __syncthreads();
  if (threadIdx.x == 0) atomicAdd(&acc[0], (double)(sred[0] + sred[1] + sred[2] + sred[3]));
}

// ---------- K2: per-(b,gt) row: align/overlaps + exact top-10 + sel mark ----------

__global__ __launch_bounds__(256) void k_assign_rows(const float* __restrict__ f0,
                                                     const float* __restrict__ f1,
                                                     const float* __restrict__ f2,
                                                     const float* __restrict__ ann,
                                                     const float4* __restrict__ pbox,
                                                     float* __restrict__ alg,
                                                     float* __restrict__ ovl,
                                                     unsigned char* __restrict__ sel) {
  __shared__ float s_al[NA_TOT];        // 33.6 KB
  __shared__ float s_v[4];
  __shared__ int   s_i[4];
  __shared__ int   s_top[TOPKN];

  int bm = blockIdx.x;
  int b = bm / MB;
  const float* g = ann + (size_t)bm * 6;
  float cx = g[1], cy = g[2], w_ = g[3], h_ = g[4];
  float gx1 = (cx - w_ * 0.5f) * 640.f, gy1 = (cy - h_ * 0.5f) * 640.f;
  float gx2 = (cx + w_ * 0.5f) * 640.f, gy2 = (cy + h_ * 0.5f) * 640.f;
  int label = (int)g[5];
  bool valid = (gx1 + gy1 + gx2 + gy2) > 0.f;

  size_t rowoff = (size_t)bm * NA_TOT;
  for (int a = threadIdx.x; a < NA_TOT; a += 256) {
    float stride, ax, ay; anchor_geom(a, stride, ax, ay);
    float axp = ax * stride, ayp = ay * stride;
    float mn = fminf(fminf(axp - gx1, ayp - gy1), fminf(gx2 - axp, gy2 - ayp));
    float al = 0.f, ov = 0.f;
    if (valid && mn > 1e-9f) {
      float4 pb = pbox[b * NA_TOT + a];
      float px1 = pb.x * stride, py1 = pb.y * stride;
      float px2 = pb.z * stride, py2 = pb.w * stride;
      ov = fmaxf(ciou_f(gx1, gy1, gx2, gy2, px1, py1, px2, py2), 0.f);
      int hw, pos; const float* f = feat_sel(f0, f1, f2, a, hw, pos);
      float xs = f[((size_t)b * NC_TOT + 64 + label) * hw + pos];
      float sg = 1.f / (1.f + expf(-xs));
      float o2 = ov * ov;
      al = sqrtf(sg) * (o2 * o2 * o2);   // s^0.5 * o^6
    }
    alg[rowoff + a] = al;
    ovl[rowoff + a] = ov;
    sel[rowoff + a] = 0;
    s_al[a] = al;
  }
  __syncthreads();

  // exact top-10: (value desc, index asc) — matches jax.lax.top_k tie-breaking
  for (int k = 0; k < TOPKN; k++) {
    float bv = -1.f; int bi = NA_TOT;
    for (int a = threadIdx.x; a < NA_TOT; a += 256) {
      float v = s_al[a];
      if (v > bv || (v == bv && a < bi)) { bv = v; bi = a; }
    }
    for (int o = 32; o > 0; o >>= 1) {
      float xv = __shfl_down(bv, o, 64);
      int   xi = __shfl_down(bi, o, 64);
      if (xv > bv || (xv == bv && xi < bi)) { bv = xv; bi = xi; }
    }
    if ((threadIdx.x & 63) == 0) { s_v[threadIdx.x >> 6] = bv; s_i[threadIdx.x >> 6] = bi; }
    __syncthreads();
    if (threadIdx.x == 0) {
      float fv = s_v[0]; int fi = s_i[0];
      for (int w2 = 1; w2 < 4; w2++)
        if (s_v[w2] > fv || (s_v[w2] == fv && s_i[w2] < fi)) { fv = s_v[w2]; fi = s_i[w2]; }
      s_top[k] = fi;
      s_al[fi] = -1.f;   // exclude from later picks (all real values >= 0)
    }
    __syncthreads();
  }

  if (threadIdx.x < TOPKN && valid) {
    int a = s_top[threadIdx.x];
    float stride, ax, ay; anchor_geom(a, stride, ax, ay);
    float axp = ax * stride, ayp = ay * stride;
    float mn = fminf(fminf(axp - gx1, ayp - gy1), fminf(gx2 - axp, gy2 - ayp));
    if (mn > 1e-9f) sel[rowoff + a] = 1;   // mask_pos = topk ∧ mask_in_gts ∧ valid
  }
}

// ---------- K3: per-anchor fg resolution (multi-gt anchors -> argmax overlap) ----------

__global__ __launch_bounds__(256) void k_resolve(const float* __restrict__ ovl,
                                                 unsigned char* __restrict__ sel,
                                                 unsigned char* __restrict__ tgt,
                                                 unsigned char* __restrict__ fgm) {
  int idx = blockIdx.x * 256 + threadIdx.x;
  int b = idx / NA_TOT, a = idx - b * NA_TOT;
  size_t col = (size_t)b * MB * NA_TOT + a;
  int fg = 0, first = -1;
#pragma unroll
  for (int m = 0; m < MB; m++) {
    int v = sel[col + (size_t)m * NA_TOT];
    fg += v;
    if (v && first < 0) first = m;
  }
  int t, f;
  if (fg > 1) {
    float bv = ovl[col]; int bm_ = 0;
#pragma unroll
    for (int m = 1; m < MB; m++) {
      float v = ovl[col + (size_t)m * NA_TOT];
      if (v > bv) { bv = v; bm_ = m; }      // strict > keeps first max (argmax semantics)
    }
#pragma unroll
    for (int m = 0; m < MB; m++) sel[col + (size_t)m * NA_TOT] = (m == bm_) ? 1 : 0;
    t = bm_; f = 1;
  } else {
    t = (first >= 0) ? first : 0;
    f = fg;
  }
  tgt[idx] = (unsigned char)t;
  fgm[idx] = (unsigned char)f;
}

// ---------- K4: per-(b,gt) pos_align / pos_overlaps ----------

__global__ __launch_bounds__(256) void k_posmax(const float* __restrict__ alg,
                                                const float* __restrict__ ovl,
                                                const unsigned char* __restrict__ sel,
                                                float* __restrict__ pos_a,
                                                float* __restrict__ pos_o) {
  int bm = blockIdx.x;
  size_t rb = (size_t)bm * NA_TOT;
  float ma = 0.f, mo = 0.f;                 // all values >= 0
  for (int a = threadIdx.x; a < NA_TOT; a += 256) {
    if (sel[rb + a]) {
      ma = fmaxf(ma, alg[rb + a]);
      mo = fmaxf(mo, ovl[rb + a]);
    }
  }
  for (int o = 32; o > 0; o >>= 1) {
    ma = fmaxf(ma, __shfl_down(ma, o, 64));
    mo = fmaxf(mo, __shfl_down(mo, o, 64));
  }
  __shared__ float sa[4], so[4];
  if ((threadIdx.x & 63) == 0) { sa[threadIdx.x >> 6] = ma; so[threadIdx.x >> 6] = mo; }
  __syncthreads();
  if (threadIdx.x == 0) {
    pos_a[bm] = fmaxf(fmaxf(sa[0], sa[1]), fmaxf(sa[2], sa[3]));
    pos_o[bm] = fmaxf(fmaxf(so[0], so[1]), fmaxf(so[2], so[3]));
  }
}

// ---------- K5: per-anchor loss contributions (fg only) ----------

__global__ __launch_bounds__(256) void k_loss(const float* __restrict__ f0,
                                              const float* __restrict__ f1,
                                              const float* __restrict__ f2,
                                              const float* __restrict__ ann,
                                              const float4* __restrict__ pbox,
                                              const float4* __restrict__ lse4,
                                              const float* __restrict__ alg,
                                              const unsigned char* __restrict__ tgt,
                                              const unsigned char* __restrict__ fgm,
                                              const float* __restrict__ pos_a,
                                              const float* __restrict__ pos_o,
                                              double* __restrict__ acc) {
  int idx = blockIdx.x * 256 + threadIdx.x;
  int b = idx / NA_TOT, a = idx - b * NA_TOT;
  float c_cls = 0.f, c_box = 0.f, c_dfl = 0.f, c_tss = 0.f;

  if (fgm[idx]) {
    int t = tgt[idx];
    int bm = b * MB + t;
    float al = alg[(size_t)bm * NA_TOT + a];
    float norm = al * pos_o[bm] / (pos_a[bm] + 1e-9f);

    const float* g = ann + (size_t)bm * 6;
    float stride, ax, ay; anchor_geom(a, stride, ax, ay);
    int hw, pos; const float* f = feat_sel(f0, f1, f2, a, hw, pos);
    const float* base = f + (size_t)b * NC_TOT * hw + pos;

    int label = (int)g[5];
    float xs = base[(size_t)(64 + label) * hw];
    c_cls = xs * norm;      // bce(x,t) - bce(x,0) = -x*t  (subtracted at accumulate)
    c_tss = norm;

    float cx = g[1], cy = g[2], w_ = g[3], h_ = g[4];
    float inv = 1.f / stride;   // stride is 8/16/32 -> exact
    float tx1 = (cx - w_ * 0.5f) * 640.f * inv, ty1 = (cy - h_ * 0.5f) * 640.f * inv;
    float tx2 = (cx + w_ * 0.5f) * 640.f * inv, ty2 = (cy + h_ * 0.5f) * 640.f * inv;

    float4 pb = pbox[idx];
    float iou = ciou_f(pb.x, pb.y, pb.z, pb.w, tx1, ty1, tx2, ty2);  // b1=pred, b2=target
    c_box = (1.f - iou) * norm;

    float4 ls = lse4[idx];
    float ltv[4] = { ax - tx1, ay - ty1, tx2 - ax, ty2 - ay };
    float lsa[4] = { ls.x, ls.y, ls.z, ls.w };
    float dfl = 0.f;
#pragma unroll
    for (int g4 = 0; g4 < 4; g4++) {
      float tv = fminf(fmaxf(ltv[g4], 0.f), 14.99f);
      int   tl = (int)tv;
      float wl = (float)(tl + 1) - tv;
      float xl = base[(size_t)(g4 * 16 + tl) * hw];
      float xr = base[(size_t)(g4 * 16 + tl + 1) * hw];
      dfl += (lsa[g4] - xl) * wl + (lsa[g4] - xr) * (1.f - wl);   // ce = lse - x
    }
    c_dfl = dfl * 0.25f * norm;
  }

  for (int o = 32; o > 0; o >>= 1) {
    c_cls += __shfl_down(c_cls, o, 64);
    c_box += __shfl_down(c_box, o, 64);
    c_dfl += __shfl_down(c_dfl, o, 64);
    c_tss += __shfl_down(c_tss, o, 64);
  }
  __shared__ float sh[4][4];
  int wv = threadIdx.x >> 6;
  if ((threadIdx.x & 63) == 0) { sh[wv][0] = c_cls; sh[wv][1] = c_box; sh[wv][2] = c_dfl; sh[wv][3] = c_tss; }
  __syncthreads();
  if (threadIdx.x == 0) {
    float t0 = sh[0][0] + sh[1][0] + sh[2][0] + sh[3][0];
    float t1 = sh[0][1] + sh[1][1] + sh[2][1] + sh[3][1];
    float t2 = sh[0][2] + sh[1][2] + sh[2][2] + sh[3][2];
    float t3 = sh[0][3] + sh[1][3] + sh[2][3] + sh[3][3];
    atomicAdd(&acc[0], -(double)t0);
    atomicAdd(&acc[1],  (double)t1);
    atomicAdd(&acc[2],  (double)t2);
    atomicAdd(&acc[3],  (double)t3);
  }
}

// ---------- K6: finalize ----------

__global__ void k_finish(const double* __restrict__ acc, float* __restrict__ out) {
  double tss = acc[3]; if (tss < 1.0) tss = 1.0;
  float lb = (float)(acc[1] / tss) * 7.5f;
  float lc = (float)(acc[0] / tss) * 0.5f;
  float ld = (float)(acc[2] / tss) * 1.5f;
  out[0] = lb + lc + ld;
  out[1] = lb;
  out[2] = lc;
  out[3] = ld;
}

// ---------- launch ----------

extern "C" void kernel_launch(void* const* d_in, const int* in_sizes, int n_in,
                              void* d_out, int out_size, void* d_ws, size_t ws_size,
                              hipStream_t stream) {
  const float* f0  = (const float*)d_in[0];
  const float* f1  = (const float*)d_in[1];
  const float* f2  = (const float*)d_in[2];
  const float* ann = (const float*)d_in[3];

  char* p = (char*)d_ws;
  size_t off = 0;
  double* acc = (double*)(p + off);            off += 64;
  float4* pbox = (float4*)(p + off);           off += (size_t)BSZ * NA_TOT * 16;
  float4* lse4 = (float4*)(p + off);           off += (size_t)BSZ * NA_TOT * 16;
  float* alg = (float*)(p + off);              off += (size_t)BSZ * MB * NA_TOT * 4;
  float* ovl = (float*)(p + off);              off += (size_t)BSZ * MB * NA_TOT * 4;
  unsigned char* sel = (unsigned char*)(p + off); off += (size_t)BSZ * MB * NA_TOT;
  unsigned char* tgt = (unsigned char*)(p + off); off += (size_t)BSZ * NA_TOT;
  unsigned char* fgm = (unsigned char*)(p + off); off += (size_t)BSZ * NA_TOT;
  float* pos_a = (float*)(p + off);            off += (size_t)BSZ * MB * 4;
  float* pos_o = (float*)(p + off);            off += (size_t)BSZ * MB * 4;

  hipMemsetAsync(acc, 0, 64, stream);

  const int NBLK = (BSZ * NA_TOT) / 256;   // 134400/256 = 525 exactly
  k_prep<<<NBLK, 256, 0, stream>>>(f0, f1, f2, pbox, lse4, acc);
  k_assign_rows<<<BSZ * MB, 256, 0, stream>>>(f0, f1, f2, ann, pbox, alg, ovl, sel);
  k_resolve<<<NBLK, 256, 0, stream>>>(ovl, sel, tgt, fgm);
  k_posmax<<<BSZ * MB, 256, 0, stream>>>(alg, ovl, sel, pos_a, pos_o);
  k_loss<<<NBLK, 256, 0, stream>>>(f0, f1, f2, ann, pbox, lse4, alg, tgt, fgm, pos_a, pos_o, acc);
  k_finish<<<1, 1, 0, stream>>>(acc, (float*)d_out);
}

// Round 2
// 203.090 us; speedup vs baseline: 1.2940x; 1.2940x over previous
//
#include <hip/hip_runtime.h>

#define NA_TOT 8400
#define A0 6400
#define A1 8000
#define NC_TOT 144
#define BSZ 16
#define MB 20
#define TOPKN 10
#define NCLS 80

// ---------- helpers ----------

__device__ __forceinline__ const float* feat_sel(const float* f0, const float* f1,
                                                 const float* f2, int a, int& hw, int& pos) {
  if (a < A0) { hw = 6400; pos = a;      return f0; }
  if (a < A1) { hw = 1600; pos = a - A0; return f1; }
  hw = 400; pos = a - A1; return f2;
}

__device__ __forceinline__ void anchor_geom(int a, float& stride, float& ax, float& ay) {
  int pos, w;
  if (a < A0)      { pos = a;      w = 80; stride = 8.f;  }
  else if (a < A1) { pos = a - A0; w = 40; stride = 16.f; }
  else             { pos = a - A1; w = 20; stride = 32.f; }
  int y = pos / w, x = pos - y * w;
  ax = (float)x + 0.5f; ay = (float)y + 0.5f;
}

// CIoU exactly per reference (_ciou). b1 = first arg box, b2 = second.
__device__ __forceinline__ float ciou_f(float b1x1, float b1y1, float b1x2, float b1y2,
                                        float b2x1, float b2y1, float b2x2, float b2y2) {
  const float eps = 1e-7f;
  float w1 = b1x2 - b1x1, h1 = b1y2 - b1y1 + eps;
  float w2 = b2x2 - b2x1, h2 = b2y2 - b2y1 + eps;
  float iw = fminf(b1x2, b2x2) - fmaxf(b1x1, b2x1);
  float ih = fminf(b1y2, b2y2) - fmaxf(b1y1, b2y1);
  float inter = fmaxf(iw, 0.f) * fmaxf(ih, 0.f);
  float uni = w1 * h1 + w2 * h2 - inter + eps;
  float iou = inter / uni;
  float cw = fmaxf(b1x2, b2x2) - fminf(b1x1, b2x1);
  float ch = fmaxf(b1y2, b2y2) - fminf(b1y1, b2y1);
  float c2 = cw * cw + ch * ch + eps;
  float dx = b2x1 + b2x2 - b1x1 - b1x2;
  float dy = b2y1 + b2y2 - b1y1 - b1y2;
  float rho2 = (dx * dx + dy * dy) * 0.25f;
  float dat = atanf(w2 / h2) - atanf(w1 / h1);
  float v = 0.4052847345693511f * dat * dat;      // 4/pi^2
  float alpha = v / (v - iou + (1.f + eps));
  return iou - (rho2 / c2 + v * alpha);
}

__device__ __forceinline__ bool better(float v1, int i1, float v2, int i2) {
  return (v1 > v2) || (v1 == v2 && i1 < i2);
}

// ---------- K1: prep — 4 waves cooperate on 64 anchors ----------
// wave w: softmax of reg-group w (16 ch) + BCE(x,0) of classes [w*20, w*20+20)

#define PREP_TILES 132   // ceil(8400/64)

__global__ __launch_bounds__(256) void k_prep(const float* __restrict__ f0,
                                              const float* __restrict__ f1,
                                              const float* __restrict__ f2,
                                              float4* __restrict__ pbox,
                                              float4* __restrict__ lse4,
                                              double* __restrict__ acc) {
  __shared__ float s_d[64][5];
  __shared__ float s_ls[64][5];
  __shared__ float s_red[4];
  int tile = blockIdx.x % PREP_TILES;
  int b    = blockIdx.x / PREP_TILES;
  int w = threadIdx.x >> 6, l = threadIdx.x & 63;
  int a = tile * 64 + l;
  float bce = 0.f;
  if (a < NA_TOT) {
    int hw, pos; const float* f = feat_sel(f0, f1, f2, a, hw, pos);
    const float* base = f + (size_t)b * NC_TOT * hw + pos;
    float v[16]; float m = -1e30f;
#pragma unroll
    for (int i = 0; i < 16; i++) { v[i] = base[(size_t)(w * 16 + i) * hw]; m = fmaxf(m, v[i]); }
    float s = 0.f, ws = 0.f;
#pragma unroll
    for (int i = 0; i < 16; i++) { float e = expf(v[i] - m); s += e; ws += e * (float)i; }
    s_d[l][w]  = ws / s;
    s_ls[l][w] = m + logf(s);
#pragma unroll
    for (int j = 0; j < 20; j++) {
      float x = base[(size_t)(64 + w * 20 + j) * hw];
      bce += fmaxf(x, 0.f) + log1pf(expf(-fabsf(x)));
    }
  }
  for (int o = 32; o > 0; o >>= 1) bce += __shfl_down(bce, o, 64);
  if (l == 0) s_red[w] = bce;
  __syncthreads();
  if (threadIdx.x == 0)
    atomicAdd(&acc[0], (double)(s_red[0] + s_red[1] + s_red[2] + s_red[3]));
  if (threadIdx.x < 64 && a < NA_TOT) {
    float stride, ax, ay; anchor_geom(a, stride, ax, ay);
    int idx = b * NA_TOT + a;
    pbox[idx] = make_float4(ax - s_d[l][0], ay - s_d[l][1], ax + s_d[l][2], ay + s_d[l][3]);
    lse4[idx] = make_float4(s_ls[l][0], s_ls[l][1], s_ls[l][2], s_ls[l][3]);
  }
}

// ---------- K2: align/overlap, flat over (b,gt,anchor) ----------

__global__ __launch_bounds__(256) void k_align(const float* __restrict__ f0,
                                               const float* __restrict__ f1,
                                               const float* __restrict__ f2,
                                               const float* __restrict__ ann,
                                               const float4* __restrict__ pbox,
                                               float* __restrict__ alg,
                                               float* __restrict__ ovl,
                                               unsigned char* __restrict__ sel) {
  int idx = blockIdx.x * 256 + threadIdx.x;           // 16*20*8400 / 256 = 10500 blocks
  int bm = idx / NA_TOT, a = idx - bm * NA_TOT;
  int b = bm / MB;
  const float* g = ann + (size_t)bm * 6;
  float cx = g[1], cy = g[2], w_ = g[3], h_ = g[4];
  float gx1 = (cx - w_ * 0.5f) * 640.f, gy1 = (cy - h_ * 0.5f) * 640.f;
  float gx2 = (cx + w_ * 0.5f) * 640.f, gy2 = (cy + h_ * 0.5f) * 640.f;
  int label = (int)g[5];
  bool valid = (gx1 + gy1 + gx2 + gy2) > 0.f;

  float stride, ax, ay; anchor_geom(a, stride, ax, ay);
  float axp = ax * stride, ayp = ay * stride;
  float mn = fminf(fminf(axp - gx1, ayp - gy1), fminf(gx2 - axp, gy2 - ayp));
  float al = 0.f, ov = 0.f;
  if (valid && mn > 1e-9f) {
    float4 pb = pbox[b * NA_TOT + a];
    float px1 = pb.x * stride, py1 = pb.y * stride;
    float px2 = pb.z * stride, py2 = pb.w * stride;
    ov = fmaxf(ciou_f(gx1, gy1, gx2, gy2, px1, py1, px2, py2), 0.f);
    int hw, pos; const float* f = feat_sel(f0, f1, f2, a, hw, pos);
    float xs = f[((size_t)b * NC_TOT + 64 + label) * hw + pos];
    float sg = 1.f / (1.f + expf(-xs));
    float o2 = ov * ov;
    al = sqrtf(sg) * (o2 * o2 * o2);   // s^0.5 * o^6
  }
  alg[idx] = al;
  ovl[idx] = ov;
  sel[idx] = 0;
}

// ---------- K3: exact top-10 per (b,gt) row: reg-local top10 + 10-round merge ----------

__global__ __launch_bounds__(256) void k_topk(const float* __restrict__ alg,
                                              const float* __restrict__ ann,
                                              unsigned char* __restrict__ sel) {
  __shared__ float s_v[4];
  __shared__ int   s_i[4];
  __shared__ float s_bv;
  __shared__ int   s_bi;
  __shared__ int   s_top[TOPKN];

  int bm = blockIdx.x;
  const float* row = alg + (size_t)bm * NA_TOT;
  const float* g = ann + (size_t)bm * 6;
  float cx = g[1], cy = g[2], w_ = g[3], h_ = g[4];
  float gx1 = (cx - w_ * 0.5f) * 640.f, gy1 = (cy - h_ * 0.5f) * 640.f;
  float gx2 = (cx + w_ * 0.5f) * 640.f, gy2 = (cy + h_ * 0.5f) * 640.f;
  bool valid = (gx1 + gy1 + gx2 + gy2) > 0.f;

  // per-thread sorted top-10 (value desc, index asc)
  float lv[TOPKN]; int li[TOPKN];
#pragma unroll
  for (int k = 0; k < TOPKN; k++) { lv[k] = -1.f; li[k] = 0x7fffffff; }
  for (int a = threadIdx.x; a < NA_TOT; a += 256) {
    float v = row[a];
    if (better(v, a, lv[TOPKN - 1], li[TOPKN - 1])) {
      float cv = v; int ci = a;
#pragma unroll
      for (int k = 0; k < TOPKN; k++) {
        bool bb = better(cv, ci, lv[k], li[k]);
        float tv = bb ? cv : lv[k]; int ti = bb ? ci : li[k];
        cv = bb ? lv[k] : cv;       ci = bb ? li[k] : ci;
        lv[k] = tv; li[k] = ti;
      }
    }
  }

  int wv = threadIdx.x >> 6;
  // 10 rounds of k-way merge over 256 sorted lists
  for (int k = 0; k < TOPKN; k++) {
    float bv = lv[0]; int bi = li[0];
    for (int o = 32; o > 0; o >>= 1) {
      float xv = __shfl_down(bv, o, 64);
      int   xi = __shfl_down(bi, o, 64);
      if (better(xv, xi, bv, bi)) { bv = xv; bi = xi; }
    }
    if ((threadIdx.x & 63) == 0) { s_v[wv] = bv; s_i[wv] = bi; }
    __syncthreads();
    if (threadIdx.x == 0) {
      float fv = s_v[0]; int fi = s_i[0];
      for (int q = 1; q < 4; q++)
        if (better(s_v[q], s_i[q], fv, fi)) { fv = s_v[q]; fi = s_i[q]; }
      s_top[k] = fi; s_bv = fv; s_bi = fi;
    }
    __syncthreads();
    if (lv[0] == s_bv && li[0] == s_bi) {   // winner pops its head
#pragma unroll
      for (int q = 0; q < TOPKN - 1; q++) { lv[q] = lv[q + 1]; li[q] = li[q + 1]; }
      lv[TOPKN - 1] = -1.f; li[TOPKN - 1] = 0x7fffffff;
    }
    __syncthreads();
  }

  if (threadIdx.x < TOPKN && valid) {
    int a = s_top[threadIdx.x];
    float stride, ax, ay; anchor_geom(a, stride, ax, ay);
    float axp = ax * stride, ayp = ay * stride;
    float mn = fminf(fminf(axp - gx1, ayp - gy1), fminf(gx2 - axp, gy2 - ayp));
    if (mn > 1e-9f) sel[(size_t)bm * NA_TOT + a] = 1;
  }
}

// ---------- K4: per-anchor fg resolution + fused pos-max atomics ----------

__global__ __launch_bounds__(256) void k_resolve(const float* __restrict__ alg,
                                                 const float* __restrict__ ovl,
                                                 const unsigned char* __restrict__ sel,
                                                 unsigned char* __restrict__ tgt,
                                                 unsigned char* __restrict__ fgm,
                                                 unsigned int* __restrict__ pos_a,
                                                 unsigned int* __restrict__ pos_o) {
  int idx = blockIdx.x * 256 + threadIdx.x;
  int b = idx / NA_TOT, a = idx - b * NA_TOT;
  size_t col = (size_t)b * MB * NA_TOT + a;
  int fg = 0, first = -1;
#pragma unroll
  for (int m = 0; m < MB; m++) {
    int v = sel[col + (size_t)m * NA_TOT];
    fg += v;
    if (v && first < 0) first = m;
  }
  int t, f;
  if (fg > 1) {
    float bv = ovl[col]; int bm_ = 0;
#pragma unroll
    for (int m = 1; m < MB; m++) {
      float v = ovl[col + (size_t)m * NA_TOT];
      if (v > bv) { bv = v; bm_ = m; }      // strict > keeps first max
    }
    t = bm_; f = 1;
  } else {
    t = (first >= 0) ? first : 0;
    f = fg;
  }
  tgt[idx] = (unsigned char)t;
  fgm[idx] = (unsigned char)f;
  if (f) {
    int bm = b * MB + t;
    float al = alg[(size_t)bm * NA_TOT + a];
    float ov = ovl[(size_t)bm * NA_TOT + a];
    atomicMax(&pos_a[bm], __float_as_uint(al));   // values >= 0: uint order == float order
    atomicMax(&pos_o[bm], __float_as_uint(ov));
  }
}

// ---------- K5: per-anchor loss contributions (fg only) ----------

__global__ __launch_bounds__(256) void k_loss(const float* __restrict__ f0,
                                              const float* __restrict__ f1,
                                              const float* __restrict__ f2,
                                              const float* __restrict__ ann,
                                              const float4* __restrict__ pbox,
                                              const float4* __restrict__ lse4,
                                              const float* __restrict__ alg,
                                              const unsigned char* __restrict__ tgt,
                                              const unsigned char* __restrict__ fgm,
                                              const unsigned int* __restrict__ pos_a,
                                              const unsigned int* __restrict__ pos_o,
                                              double* __restrict__ acc) {
  int idx = blockIdx.x * 256 + threadIdx.x;
  int b = idx / NA_TOT, a = idx - b * NA_TOT;
  float c_cls = 0.f, c_box = 0.f, c_dfl = 0.f, c_tss = 0.f;

  if (fgm[idx]) {
    int t = tgt[idx];
    int bm = b * MB + t;
    float al = alg[(size_t)bm * NA_TOT + a];
    float norm = al * __uint_as_float(pos_o[bm]) / (__uint_as_float(pos_a[bm]) + 1e-9f);

    const float* g = ann + (size_t)bm * 6;
    float stride, ax, ay; anchor_geom(a, stride, ax, ay);
    int hw, pos; const float* f = feat_sel(f0, f1, f2, a, hw, pos);
    const float* base = f + (size_t)b * NC_TOT * hw + pos;

    int label = (int)g[5];
    float xs = base[(size_t)(64 + label) * hw];
    c_cls = xs * norm;      // bce(x,t) - bce(x,0) = -x*t  (sign applied at accumulate)
    c_tss = norm;

    float cx = g[1], cy = g[2], w_ = g[3], h_ = g[4];
    float inv = 1.f / stride;
    float tx1 = (cx - w_ * 0.5f) * 640.f * inv, ty1 = (cy - h_ * 0.5f) * 640.f * inv;
    float tx2 = (cx + w_ * 0.5f) * 640.f * inv, ty2 = (cy + h_ * 0.5f) * 640.f * inv;

    float4 pb = pbox[idx];
    float iou = ciou_f(pb.x, pb.y, pb.z, pb.w, tx1, ty1, tx2, ty2);
    c_box = (1.f - iou) * norm;

    float4 ls = lse4[idx];
    float ltv[4] = { ax - tx1, ay - ty1, tx2 - ax, ty2 - ay };
    float lsa[4] = { ls.x, ls.y, ls.z, ls.w };
    float dfl = 0.f;
#pragma unroll
    for (int g4 = 0; g4 < 4; g4++) {
      float tv = fminf(fmaxf(ltv[g4], 0.f), 14.99f);
      int   tl = (int)tv;
      float wl = (float)(tl + 1) - tv;
      float xl = base[(size_t)(g4 * 16 + tl) * hw];
      float xr = base[(size_t)(g4 * 16 + tl + 1) * hw];
      dfl += (lsa[g4] - xl) * wl + (lsa[g4] - xr) * (1.f - wl);   // ce = lse - x
    }
    c_dfl = dfl * 0.25f * norm;
  }

  for (int o = 32; o > 0; o >>= 1) {
    c_cls += __shfl_down(c_cls, o, 64);
    c_box += __shfl_down(c_box, o, 64);
    c_dfl += __shfl_down(c_dfl, o, 64);
    c_tss += __shfl_down(c_tss, o, 64);
  }
  __shared__ float sh[4][4];
  int wv = threadIdx.x >> 6;
  if ((threadIdx.x & 63) == 0) { sh[wv][0] = c_cls; sh[wv][1] = c_box; sh[wv][2] = c_dfl; sh[wv][3] = c_tss; }
  __syncthreads();
  if (threadIdx.x == 0) {
    float t0 = sh[0][0] + sh[1][0] + sh[2][0] + sh[3][0];
    float t1 = sh[0][1] + sh[1][1] + sh[2][1] + sh[3][1];
    float t2 = sh[0][2] + sh[1][2] + sh[2][2] + sh[3][2];
    float t3 = sh[0][3] + sh[1][3] + sh[2][3] + sh[3][3];
    atomicAdd(&acc[0], -(double)t0);
    atomicAdd(&acc[1],  (double)t1);
    atomicAdd(&acc[2],  (double)t2);
    atomicAdd(&acc[3],  (double)t3);
  }
}

// ---------- K6: finalize ----------

__global__ void k_finish(const double* __restrict__ acc, float* __restrict__ out) {
  double tss = acc[3]; if (tss < 1.0) tss = 1.0;
  float lb = (float)(acc[1] / tss) * 7.5f;
  float lc = (float)(acc[0] / tss) * 0.5f;
  float ld = (float)(acc[2] / tss) * 1.5f;
  out[0] = lb + lc + ld;
  out[1] = lb;
  out[2] = lc;
  out[3] = ld;
}

// ---------- launch ----------

extern "C" void kernel_launch(void* const* d_in, const int* in_sizes, int n_in,
                              void* d_out, int out_size, void* d_ws, size_t ws_size,
                              hipStream_t stream) {
  const float* f0  = (const float*)d_in[0];
  const float* f1  = (const float*)d_in[1];
  const float* f2  = (const float*)d_in[2];
  const float* ann = (const float*)d_in[3];

  char* p = (char*)d_ws;
  size_t off = 0;
  double* acc = (double*)(p + off);               off += 64;
  unsigned int* pos_a = (unsigned int*)(p + off); off += (size_t)BSZ * MB * 4;     // 1280
  unsigned int* pos_o = (unsigned int*)(p + off); off += (size_t)BSZ * MB * 4;     // 1280
  size_t zero_bytes = off;                                                          // 2624
  float4* pbox = (float4*)(p + off);              off += (size_t)BSZ * NA_TOT * 16;
  float4* lse4 = (float4*)(p + off);              off += (size_t)BSZ * NA_TOT * 16;
  float* alg = (float*)(p + off);                 off += (size_t)BSZ * MB * NA_TOT * 4;
  float* ovl = (float*)(p + off);                 off += (size_t)BSZ * MB * NA_TOT * 4;
  unsigned char* sel = (unsigned char*)(p + off); off += (size_t)BSZ * MB * NA_TOT;
  unsigned char* tgt = (unsigned char*)(p + off); off += (size_t)BSZ * NA_TOT;
  unsigned char* fgm = (unsigned char*)(p + off); off += (size_t)BSZ * NA_TOT;

  hipMemsetAsync(acc, 0, zero_bytes, stream);

  const int NBLK = (BSZ * NA_TOT) / 256;   // 525
  k_prep<<<BSZ * PREP_TILES, 256, 0, stream>>>(f0, f1, f2, pbox, lse4, acc);
  k_align<<<(BSZ * MB * NA_TOT) / 256, 256, 0, stream>>>(f0, f1, f2, ann, pbox, alg, ovl, sel);
  k_topk<<<BSZ * MB, 256, 0, stream>>>(alg, ann, sel);
  k_resolve<<<NBLK, 256, 0, stream>>>(alg, ovl, sel, tgt, fgm, pos_a, pos_o);
  k_loss<<<NBLK, 256, 0, stream>>>(f0, f1, f2, ann, pbox, lse4, alg, tgt, fgm, pos_a, pos_o, acc);
  k_finish<<<1, 1, 0, stream>>>(acc, (float*)d_out);
}

// Round 4
// 191.749 us; speedup vs baseline: 1.3705x; 1.0591x over previous
//
#include <hip/hip_runtime.h>

#define NA_TOT 8400
#define A0 6400
#define A1 8000
#define NC_TOT 144
#define BSZ 16
#define MB 20
#define TOPKN 10
#define NCLS 80

// ---------- helpers ----------

__device__ __forceinline__ const float* feat_sel(const float* f0, const float* f1,
                                                 const float* f2, int a, int& hw, int& pos) {
  if (a < A0) { hw = 6400; pos = a;      return f0; }
  if (a < A1) { hw = 1600; pos = a - A0; return f1; }
  hw = 400; pos = a - A1; return f2;
}

__device__ __forceinline__ void anchor_geom(int a, float& stride, float& ax, float& ay) {
  int pos, w;
  if (a < A0)      { pos = a;      w = 80; stride = 8.f;  }
  else if (a < A1) { pos = a - A0; w = 40; stride = 16.f; }
  else             { pos = a - A1; w = 20; stride = 32.f; }
  int y = pos / w, x = pos - y * w;
  ax = (float)x + 0.5f; ay = (float)y + 0.5f;
}

// CIoU exactly per reference (_ciou). b1 = first arg box, b2 = second. (used in k_loss)
__device__ __forceinline__ float ciou_f(float b1x1, float b1y1, float b1x2, float b1y2,
                                        float b2x1, float b2y1, float b2x2, float b2y2) {
  const float eps = 1e-7f;
  float w1 = b1x2 - b1x1, h1 = b1y2 - b1y1 + eps;
  float w2 = b2x2 - b2x1, h2 = b2y2 - b2y1 + eps;
  float iw = fminf(b1x2, b2x2) - fmaxf(b1x1, b2x1);
  float ih = fminf(b1y2, b2y2) - fmaxf(b1y1, b2y1);
  float inter = fmaxf(iw, 0.f) * fmaxf(ih, 0.f);
  float uni = w1 * h1 + w2 * h2 - inter + eps;
  float iou = inter / uni;
  float cw = fmaxf(b1x2, b2x2) - fminf(b1x1, b2x1);
  float ch = fmaxf(b1y2, b2y2) - fminf(b1y1, b2y1);
  float c2 = cw * cw + ch * ch + eps;
  float dx = b2x1 + b2x2 - b1x1 - b1x2;
  float dy = b2y1 + b2y2 - b1y1 - b1y2;
  float rho2 = (dx * dx + dy * dy) * 0.25f;
  float dat = atanf(w2 / h2) - atanf(w1 / h1);
  float v = 0.4052847345693511f * dat * dat;      // 4/pi^2
  float alpha = v / (v - iou + (1.f + eps));
  return iou - (rho2 / c2 + v * alpha);
}

__device__ __forceinline__ bool better(float v1, int i1, float v2, int i2) {
  return (v1 > v2) || (v1 == v2 && i1 < i2);
}

// ---------- K0: GT table — one thread per (b,gt). 320 threads total. ----------
// {gx1,gy1,gx2,gy2, area1, atan(w1/h1), label, valid}

__global__ void k_gtt(const float* __restrict__ ann, float* __restrict__ gtt) {
  int bm = threadIdx.x;                 // launched with exactly BSZ*MB threads
  const float* g = ann + bm * 6;
  float cx = g[1], cy = g[2], w_ = g[3], h_ = g[4];
  float gx1 = (cx - w_ * 0.5f) * 640.f, gy1 = (cy - h_ * 0.5f) * 640.f;
  float gx2 = (cx + w_ * 0.5f) * 640.f, gy2 = (cy + h_ * 0.5f) * 640.f;
  float w1 = gx2 - gx1, h1 = gy2 - gy1 + 1e-7f;
  float* o = gtt + bm * 8;
  o[0] = gx1; o[1] = gy1; o[2] = gx2; o[3] = gy2;
  o[4] = w1 * h1;
  o[5] = atanf(w1 / h1);
  o[6] = g[5];
  o[7] = ((gx1 + gy1 + gx2 + gy2) > 0.f) ? 1.f : 0.f;
}

// ---------- K1: prep — 4 waves cooperate on 64 anchors ----------

#define PREP_TILES 132   // ceil(8400/64)

__global__ __launch_bounds__(256) void k_prep(const float* __restrict__ f0,
                                              const float* __restrict__ f1,
                                              const float* __restrict__ f2,
                                              float4* __restrict__ pbox,
                                              float4* __restrict__ lse4,
                                              unsigned int* __restrict__ selmask,
                                              double* __restrict__ acc) {
  __shared__ float s_d[64][5];
  __shared__ float s_ls[64][5];
  __shared__ float s_red[4];

  int tile = blockIdx.x % PREP_TILES;
  int b    = blockIdx.x / PREP_TILES;
  int w = threadIdx.x >> 6, l = threadIdx.x & 63;
  int a = tile * 64 + l;
  float bce = 0.f;
  if (a < NA_TOT) {
    int hw, pos; const float* f = feat_sel(f0, f1, f2, a, hw, pos);
    const float* base = f + (size_t)b * NC_TOT * hw + pos;
    // softmax over reg-group w (libm exp/log: feeds pred boxes -> discrete topk; keep exact)
    int co = w * 16 * hw;
    float v[16]; float m = -1e30f;
#pragma unroll
    for (int i = 0; i < 16; i++) { v[i] = base[co + i * hw]; m = fmaxf(m, v[i]); }
    float s = 0.f, ws = 0.f;
#pragma unroll
    for (int i = 0; i < 16; i++) { float e = expf(v[i] - m); s += e; ws += e * (float)i; }
    s_d[l][w]  = ws / s;
    s_ls[l][w] = m + logf(s);
    // BCE(x,0) over 20 classes: sum log1p(e_j) == log(prod (1+e_j)); smooth sum -> fast exp ok
    int cc = (64 + w * 20) * hw;
    float relu = 0.f, pr0 = 1.f, pr1 = 1.f;
#pragma unroll
    for (int j = 0; j < 20; j += 2) {
      float x0 = base[cc + j * hw];
      float x1 = base[cc + (j + 1) * hw];
      relu += fmaxf(x0, 0.f) + fmaxf(x1, 0.f);
      pr0 *= 1.f + __expf(-fabsf(x0));
      pr1 *= 1.f + __expf(-fabsf(x1));
    }
    bce = relu + logf(pr0 * pr1);
  }
  for (int o = 32; o > 0; o >>= 1) bce += __shfl_down(bce, o, 64);
  if (l == 0) s_red[w] = bce;
  __syncthreads();
  if (threadIdx.x == 0)
    atomicAdd(&acc[0], (double)(s_red[0] + s_red[1] + s_red[2] + s_red[3]));
  if (threadIdx.x < 64 && a < NA_TOT) {
    float stride, ax, ay; anchor_geom(a, stride, ax, ay);
    int idx = b * NA_TOT + a;
    pbox[idx] = make_float4(ax - s_d[l][0], ay - s_d[l][1], ax + s_d[l][2], ay + s_d[l][3]);
    lse4[idx] = make_float4(s_ls[l][0], s_ls[l][1], s_ls[l][2], s_ls[l][3]);
    selmask[idx] = 0u;
  }
}

// ---------- K2: align/overlap, flat over (b,gt,anchor), GT side hoisted ----------

__global__ __launch_bounds__(256) void k_align(const float* __restrict__ f0,
                                               const float* __restrict__ f1,
                                               const float* __restrict__ f2,
                                               const float* __restrict__ gtt,
                                               const float4* __restrict__ pbox,
                                               float* __restrict__ alg,
                                               float* __restrict__ ovl) {
  int idx = blockIdx.x * 256 + threadIdx.x;           // 16*20*8400 / 256 = 10500 blocks
  int bm = idx / NA_TOT, a = idx - bm * NA_TOT;
  int b = bm / MB;
  float4 t0 = *(const float4*)(gtt + bm * 8);
  float4 t1 = *(const float4*)(gtt + bm * 8 + 4);
  float gx1 = t0.x, gy1 = t0.y, gx2 = t0.z, gy2 = t0.w;
  float area1 = t1.x, atn1 = t1.y;
  int label = (int)t1.z;
  bool valid = t1.w > 0.f;

  float stride, ax, ay; anchor_geom(a, stride, ax, ay);
  float axp = ax * stride, ayp = ay * stride;
  float mn = fminf(fminf(axp - gx1, ayp - gy1), fminf(gx2 - axp, gy2 - ayp));
  float al = 0.f, ov = 0.f;
  if (valid && mn > 1e-9f) {
    const float eps = 1e-7f;
    float4 pb = pbox[b * NA_TOT + a];
    float px1 = pb.x * stride, py1 = pb.y * stride;
    float px2 = pb.z * stride, py2 = pb.w * stride;
    // inlined _ciou(b1=gt, b2=pred), gt-side terms precomputed (bit-identical op order)
    float w2 = px2 - px1, h2 = py2 - py1 + eps;
    float iw = fminf(gx2, px2) - fmaxf(gx1, px1);
    float ih = fminf(gy2, py2) - fmaxf(gy1, py1);
    float inter = fmaxf(iw, 0.f) * fmaxf(ih, 0.f);
    float uni = area1 + w2 * h2 - inter + eps;
    float iou = inter / uni;
    float cw = fmaxf(gx2, px2) - fminf(gx1, px1);
    float ch = fmaxf(gy2, py2) - fminf(gy1, py1);
    float c2 = cw * cw + ch * ch + eps;
    float dx = px1 + px2 - gx1 - gx2;
    float dy = py1 + py2 - gy1 - gy2;
    float rho2 = (dx * dx + dy * dy) * 0.25f;
    float dat = atanf(w2 / h2) - atn1;
    float v = 0.4052847345693511f * dat * dat;
    float alpha = v / (v - iou + (1.f + eps));
    ov = fmaxf(iou - (rho2 / c2 + v * alpha), 0.f);

    int hw, pos; const float* f = feat_sel(f0, f1, f2, a, hw, pos);
    float xs = f[((size_t)b * NC_TOT + 64 + label) * hw + pos];
    float sg = 1.f / (1.f + expf(-xs));
    float o2 = ov * ov;
    al = sqrtf(sg) * (o2 * o2 * o2);   // s^0.5 * o^6
  }
  alg[idx] = al;
  ovl[idx] = ov;
}

// ---------- K3: exact top-10 per (b,gt) row: reg-local top10 + 10-round merge ----------

__global__ __launch_bounds__(256) void k_topk(const float* __restrict__ alg,
                                              const float* __restrict__ gtt,
                                              unsigned int* __restrict__ selmask) {
  __shared__ float s_v[4];
  __shared__ int   s_i[4];
  __shared__ float s_bv;
  __shared__ int   s_bi;
  __shared__ int   s_top[TOPKN];

  int bm = blockIdx.x;
  int b = bm / MB, m = bm - b * MB;
  const float* row = alg + (size_t)bm * NA_TOT;
  float4 t0 = *(const float4*)(gtt + bm * 8);
  float4 t1 = *(const float4*)(gtt + bm * 8 + 4);
  float gx1 = t0.x, gy1 = t0.y, gx2 = t0.z, gy2 = t0.w;
  bool valid = t1.w > 0.f;

  // per-thread sorted top-10 (value desc, index asc)
  float lv[TOPKN]; int li[TOPKN];
#pragma unroll
  for (int k = 0; k < TOPKN; k++) { lv[k] = -1.f; li[k] = 0x7fffffff; }
  for (int a = threadIdx.x; a < NA_TOT; a += 256) {
    float v = row[a];
    if (better(v, a, lv[TOPKN - 1], li[TOPKN - 1])) {
      float cv = v; int ci = a;
#pragma unroll
      for (int k = 0; k < TOPKN; k++) {
        bool bb = better(cv, ci, lv[k], li[k]);
        float tv = bb ? cv : lv[k]; int ti = bb ? ci : li[k];
        cv = bb ? lv[k] : cv;       ci = bb ? li[k] : ci;
        lv[k] = tv; li[k] = ti;
      }
    }
  }

  int wv = threadIdx.x >> 6;
  for (int k = 0; k < TOPKN; k++) {
    float bv = lv[0]; int bi = li[0];
    for (int o = 32; o > 0; o >>= 1) {
      float xv = __shfl_down(bv, o, 64);
      int   xi = __shfl_down(bi, o, 64);
      if (better(xv, xi, bv, bi)) { bv = xv; bi = xi; }
    }
    if ((threadIdx.x & 63) == 0) { s_v[wv] = bv; s_i[wv] = bi; }
    __syncthreads();
    if (threadIdx.x == 0) {
      float fv = s_v[0]; int fi = s_i[0];
      for (int q = 1; q < 4; q++)
        if (better(s_v[q], s_i[q], fv, fi)) { fv = s_v[q]; fi = s_i[q]; }
      s_top[k] = fi; s_bv = fv; s_bi = fi;
    }
    __syncthreads();
    if (lv[0] == s_bv && li[0] == s_bi) {   // winner pops its head
#pragma unroll
      for (int q = 0; q < TOPKN - 1; q++) { lv[q] = lv[q + 1]; li[q] = li[q + 1]; }
      lv[TOPKN - 1] = -1.f; li[TOPKN - 1] = 0x7fffffff;
    }
    __syncthreads();
  }

  if (threadIdx.x < TOPKN && valid) {
    int a = s_top[threadIdx.x];
    float stride, ax, ay; anchor_geom(a, stride, ax, ay);
    float axp = ax * stride, ayp = ay * stride;
    float mn = fminf(fminf(axp - gx1, ayp - gy1), fminf(gx2 - axp, gy2 - ayp));
    if (mn > 1e-9f) atomicOr(&selmask[b * NA_TOT + a], 1u << m);
  }
}

// ---------- K4: per-anchor fg resolution + fused pos-max atomics ----------

__global__ __launch_bounds__(256) void k_resolve(const float* __restrict__ alg,
                                                 const float* __restrict__ ovl,
                                                 const unsigned int* __restrict__ selmask,
                                                 unsigned char* __restrict__ tgt,
                                                 unsigned char* __restrict__ fgm,
                                                 unsigned int* __restrict__ pos_a,
                                                 unsigned int* __restrict__ pos_o) {
  int idx = blockIdx.x * 256 + threadIdx.x;
  int b = idx / NA_TOT, a = idx - b * NA_TOT;
  size_t col = (size_t)b * MB * NA_TOT + a;
  unsigned int mask = selmask[idx];
  int fg = __popc(mask);
  int t, f;
  if (fg > 1) {
    // reference: argmax of overlaps over ALL m (masked values are 0), first-max wins
    float bv = ovl[col]; int bm_ = 0;
#pragma unroll
    for (int m = 1; m < MB; m++) {
      float v = ovl[col + (size_t)m * NA_TOT];
      if (v > bv) { bv = v; bm_ = m; }
    }
    t = bm_; f = 1;
  } else {
    t = mask ? (__ffs(mask) - 1) : 0;
    f = fg;
  }
  tgt[idx] = (unsigned char)t;
  fgm[idx] = (unsigned char)f;
  if (f) {
    int bm = b * MB + t;
    float al = alg[(size_t)bm * NA_TOT + a];
    float ov = ovl[(size_t)bm * NA_TOT + a];
    atomicMax(&pos_a[bm], __float_as_uint(al));   // values >= 0: uint order == float order
    atomicMax(&pos_o[bm], __float_as_uint(ov));
  }
}

// ---------- K5: per-anchor loss contributions (fg only) ----------

__global__ __launch_bounds__(256) void k_loss(const float* __restrict__ f0,
                                              const float* __restrict__ f1,
                                              const float* __restrict__ f2,
                                              const float* __restrict__ ann,
                                              const float4* __restrict__ pbox,
                                              const float4* __restrict__ lse4,
                                              const float* __restrict__ alg,
                                              const unsigned char* __restrict__ tgt,
                                              const unsigned char* __restrict__ fgm,
                                              const unsigned int* __restrict__ pos_a,
                                              const unsigned int* __restrict__ pos_o,
                                              double* __restrict__ acc) {
  int idx = blockIdx.x * 256 + threadIdx.x;
  int b = idx / NA_TOT, a = idx - b * NA_TOT;
  float c_cls = 0.f, c_box = 0.f, c_dfl = 0.f, c_tss = 0.f;

  if (fgm[idx]) {
    int t = tgt[idx];
    int bm = b * MB + t;
    float al = alg[(size_t)bm * NA_TOT + a];
    float norm = al * __uint_as_float(pos_o[bm]) / (__uint_as_float(pos_a[bm]) + 1e-9f);

    const float* g = ann + (size_t)bm * 6;
    float stride, ax, ay; anchor_geom(a, stride, ax, ay);
    int hw, pos; const float* f = feat_sel(f0, f1, f2, a, hw, pos);
    const float* base = f + (size_t)b * NC_TOT * hw + pos;

    int label = (int)g[5];
    float xs = base[(size_t)(64 + label) * hw];
    c_cls = xs * norm;      // bce(x,t) - bce(x,0) = -x*t  (sign applied at accumulate)
    c_tss = norm;

    float cx = g[1], cy = g[2], w_ = g[3], h_ = g[4];
    float inv = 1.f / stride;
    float tx1 = (cx - w_ * 0.5f) * 640.f * inv, ty1 = (cy - h_ * 0.5f) * 640.f * inv;
    float tx2 = (cx + w_ * 0.5f) * 640.f * inv, ty2 = (cy + h_ * 0.5f) * 640.f * inv;

    float4 pb = pbox[idx];
    float iou = ciou_f(pb.x, pb.y, pb.z, pb.w, tx1, ty1, tx2, ty2);
    c_box = (1.f - iou) * norm;

    float4 ls = lse4[idx];
    float ltv[4] = { ax - tx1, ay - ty1, tx2 - ax, ty2 - ay };
    float lsa[4] = { ls.x, ls.y, ls.z, ls.w };
    float dfl = 0.f;
#pragma unroll
    for (int g4 = 0; g4 < 4; g4++) {
      float tv = fminf(fmaxf(ltv[g4], 0.f), 14.99f);
      int   tl = (int)tv;
      float wl = (float)(tl + 1) - tv;
      float xl = base[(size_t)(g4 * 16 + tl) * hw];
      float xr = base[(size_t)(g4 * 16 + tl + 1) * hw];
      dfl += (lsa[g4] - xl) * wl + (lsa[g4] - xr) * (1.f - wl);   // ce = lse - x
    }
    c_dfl = dfl * 0.25f * norm;
  }

  for (int o = 32; o > 0; o >>= 1) {
    c_cls += __shfl_down(c_cls, o, 64);
    c_box += __shfl_down(c_box, o, 64);
    c_dfl += __shfl_down(c_dfl, o, 64);
    c_tss += __shfl_down(c_tss, o, 64);
  }
  __shared__ float sh[4][4];
  int wv = threadIdx.x >> 6;
  if ((threadIdx.x & 63) == 0) { sh[wv][0] = c_cls; sh[wv][1] = c_box; sh[wv][2] = c_dfl; sh[wv][3] = c_tss; }
  __syncthreads();
  if (threadIdx.x == 0) {
    float t0 = sh[0][0] + sh[1][0] + sh[2][0] + sh[3][0];
    float t1 = sh[0][1] + sh[1][1] + sh[2][1] + sh[3][1];
    float t2 = sh[0][2] + sh[1][2] + sh[2][2] + sh[3][2];
    float t3 = sh[0][3] + sh[1][3] + sh[2][3] + sh[3][3];
    atomicAdd(&acc[0], -(double)t0);
    atomicAdd(&acc[1],  (double)t1);
    atomicAdd(&acc[2],  (double)t2);
    atomicAdd(&acc[3],  (double)t3);
  }
}

// ---------- K6: finalize ----------

__global__ void k_finish(const double* __restrict__ acc, float* __restrict__ out) {
  double tss = acc[3]; if (tss < 1.0) tss = 1.0;
  float lb = (float)(acc[1] / tss) * 7.5f;
  float lc = (float)(acc[0] / tss) * 0.5f;
  float ld = (float)(acc[2] / tss) * 1.5f;
  out[0] = lb + lc + ld;
  out[1] = lb;
  out[2] = lc;
  out[3] = ld;
}

// ---------- launch ----------

extern "C" void kernel_launch(void* const* d_in, const int* in_sizes, int n_in,
                              void* d_out, int out_size, void* d_ws, size_t ws_size,
                              hipStream_t stream) {
  const float* f0  = (const float*)d_in[0];
  const float* f1  = (const float*)d_in[1];
  const float* f2  = (const float*)d_in[2];
  const float* ann = (const float*)d_in[3];

  char* p = (char*)d_ws;
  size_t off = 0;
  double* acc = (double*)(p + off);               off += 64;
  unsigned int* pos_a = (unsigned int*)(p + off); off += (size_t)BSZ * MB * 4;     // 1280
  unsigned int* pos_o = (unsigned int*)(p + off); off += (size_t)BSZ * MB * 4;     // 1280
  size_t zero_bytes = off;                                                          // 2624
  float4* pbox = (float4*)(p + off);              off += (size_t)BSZ * NA_TOT * 16;
  float4* lse4 = (float4*)(p + off);              off += (size_t)BSZ * NA_TOT * 16;
  float* alg = (float*)(p + off);                 off += (size_t)BSZ * MB * NA_TOT * 4;
  float* ovl = (float*)(p + off);                 off += (size_t)BSZ * MB * NA_TOT * 4;
  unsigned int* selmask = (unsigned int*)(p + off); off += (size_t)BSZ * NA_TOT * 4;
  float* gtt = (float*)(p + off);                 off += (size_t)BSZ * MB * 8 * 4;
  unsigned char* tgt = (unsigned char*)(p + off); off += (size_t)BSZ * NA_TOT;
  unsigned char* fgm = (unsigned char*)(p + off); off += (size_t)BSZ * NA_TOT;

  hipMemsetAsync(acc, 0, zero_bytes, stream);

  const int NBLK = (BSZ * NA_TOT) / 256;   // 525
  k_gtt<<<1, BSZ * MB, 0, stream>>>(ann, gtt);
  k_prep<<<BSZ * PREP_TILES, 256, 0, stream>>>(f0, f1, f2, pbox, lse4, selmask, acc);
  k_align<<<(BSZ * MB * NA_TOT) / 256, 256, 0, stream>>>(f0, f1, f2, gtt, pbox, alg, ovl);
  k_topk<<<BSZ * MB, 256, 0, stream>>>(alg, gtt, selmask);
  k_resolve<<<NBLK, 256, 0, stream>>>(alg, ovl, selmask, tgt, fgm, pos_a, pos_o);
  k_loss<<<NBLK, 256, 0, stream>>>(f0, f1, f2, ann, pbox, lse4, alg, tgt, fgm, pos_a, pos_o, acc);
  k_finish<<<1, 1, 0, stream>>>(acc, (float*)d_out);
}